// Round 1
// baseline (1015.071 us; speedup 1.0000x reference)
//
#include <hip/hip_runtime.h>

#define KL 1024
#define IL 8192
#define DIMV 128
#define NS 16              // row strips of 64
#define DELTA 24           // per-16-lane-group column skew
#define TROWS 8280         // padded skewed rows per strip (max t = 8191+87 = 8278)
#define SSTRIDE (TROWS*64) // floats per strip in c_sk
#define NW 130             // 130*64 = 8320 DP steps
#define PF 32              // c prefetch distance / register ring size

// ---------------- kernel 1: squared row norms + zero flags ----------------
__global__ __launch_bounds__(256) void knorms(
    const float* __restrict__ kern, const float* __restrict__ xx,
    float* __restrict__ x2, float* __restrict__ k2, int* __restrict__ flags) {
  if (blockIdx.x == 0 && threadIdx.x < NS) flags[threadIdx.x] = 0;
  const int lane = threadIdx.x & 63;
  const int row = blockIdx.x * 4 + (threadIdx.x >> 6);
  const float* src;
  float* dst;
  if (row < IL) { src = xx + (size_t)row * DIMV; dst = x2 + row; }
  else          { src = kern + (size_t)(row - IL) * DIMV; dst = k2 + (row - IL); }
  float2 v = *(const float2*)(src + lane * 2);
  float ss = v.x * v.x + v.y * v.y;
  #pragma unroll
  for (int off = 32; off > 0; off >>= 1) ss += __shfl_down(ss, off, 64);
  if (lane == 0) *dst = ss;
}

// ---------------- kernel 2: c = max(x2 + k2 - 2*x·k, 0), skew-stored ----------------
// c_sk[s][t][l] = c(row 64s+l, col j) with t = j + skew(l), skew(l) = (l&15) + DELTA*(l>>4)
__global__ __launch_bounds__(256) void kgemm(
    const float* __restrict__ kern, const float* __restrict__ xx,
    const float* __restrict__ x2, const float* __restrict__ k2,
    float* __restrict__ c_sk) {
  __shared__ float xs[128 * 68];
  __shared__ float ks[128 * 68];
  const int T = threadIdx.x;
  const int i0 = blockIdx.x * 64;  // x-row tile (DTW columns)
  const int k0 = blockIdx.y * 64;  // kernel-row tile (DTW rows)
  {
    const int rr = T >> 2;
    const int d0 = (T & 3) * 32;
    const float* xp = xx + (size_t)(i0 + rr) * DIMV + d0;
    const float* kp = kern + (size_t)(k0 + rr) * DIMV + d0;
    #pragma unroll
    for (int q = 0; q < 8; q++) {
      float4 a = *(const float4*)(xp + q * 4);
      float4 b = *(const float4*)(kp + q * 4);
      int d = d0 + q * 4;
      xs[(d+0)*68+rr] = a.x; xs[(d+1)*68+rr] = a.y; xs[(d+2)*68+rr] = a.z; xs[(d+3)*68+rr] = a.w;
      ks[(d+0)*68+rr] = b.x; ks[(d+1)*68+rr] = b.y; ks[(d+2)*68+rr] = b.z; ks[(d+3)*68+rr] = b.w;
    }
  }
  __syncthreads();
  const int ti = T & 15;
  const int tk = T >> 4;
  float acc[4][4] = {};
  #pragma unroll 4
  for (int d = 0; d < 128; d++) {
    float4 a = *(const float4*)&xs[d * 68 + ti * 4];
    float4 b = *(const float4*)&ks[d * 68 + tk * 4];
    acc[0][0] += a.x*b.x; acc[0][1] += a.x*b.y; acc[0][2] += a.x*b.z; acc[0][3] += a.x*b.w;
    acc[1][0] += a.y*b.x; acc[1][1] += a.y*b.y; acc[1][2] += a.y*b.z; acc[1][3] += a.y*b.w;
    acc[2][0] += a.z*b.x; acc[2][1] += a.z*b.y; acc[2][2] += a.z*b.z; acc[2][3] += a.z*b.w;
    acc[3][0] += a.w*b.x; acc[3][1] += a.w*b.y; acc[3][2] += a.w*b.z; acc[3][3] += a.w*b.w;
  }
  float xv[4], kv[4];
  #pragma unroll
  for (int a = 0; a < 4; a++) xv[a] = x2[i0 + ti * 4 + a];
  #pragma unroll
  for (int b = 0; b < 4; b++) kv[b] = k2[k0 + tk * 4 + b];
  __syncthreads();
  // tile[di][dk] = c(i0+di, k0+dk), reuse xs
  #pragma unroll
  for (int a = 0; a < 4; a++)
    #pragma unroll
    for (int b = 0; b < 4; b++)
      xs[(ti * 4 + a) * 64 + (tk * 4 + b)] = fmaxf(xv[a] + kv[b] - 2.f * acc[a][b], 0.f);
  __syncthreads();
  const int w = T >> 6;
  const int lane = T & 63;
  const int skew = (lane & 15) + DELTA * (lane >> 4);
  float* ob = c_sk + (size_t)blockIdx.y * SSTRIDE + (size_t)i0 * 64 + lane;
  #pragma unroll
  for (int q = 0; q < 38; q++) {
    int tt = w + q * 4;           // skewed row within this tile's span [0,150]
    int di = tt - skew;
    if (tt <= 150 && di >= 0 && di < 64) ob[tt * 64] = xs[di * 64 + lane];
  }
}

// ---------------- kernel 3: wavefront DP ----------------
__device__ __forceinline__ float f_dpp_shr1(float oldv, float src) {
  // lane m>0 of each 16-lane row gets lane m-1's src; lane m==0 keeps oldv
  int r = __builtin_amdgcn_update_dpp(__float_as_int(oldv), __float_as_int(src),
                                      0x111 /*row_shr:1*/, 0xF, 0xF, false);
  return __int_as_float(r);
}

__global__ __launch_bounds__(64) void kdp(
    const float* __restrict__ c_sk, float* __restrict__ bound,
    int* __restrict__ flags, float* __restrict__ out) {
  __shared__ float bounce[128 * 64 + 64]; // [slot][lane-col]; +dump area for lane63
  const int s = blockIdx.x;
  const int lane = threadIdx.x;
  const int g = lane >> 4;
  const int skew = (lane & 15) + DELTA * g;
  const float* cs = c_sk + (size_t)s * SSTRIDE + lane;
  float* bout = bound + (size_t)s * IL;
  const float* bin = bound + (size_t)(s - 1) * IL;
  const int rcol = (g == 0) ? 63 : (16 * g - 1); // boundary source column
  const int wand = (lane == 63) ? 0 : -1;        // lane63 writes to dump slot
  const int wbase = (lane == 63) ? (128 * 64 + 32) : lane;

  if (s == 0) { // strip 0's "row above" is the +inf border
    bounce[lane * 64 + 63] = INFINITY;
    bounce[(lane + 64) * 64 + 63] = INFINITY;
  }
  // c prefetch ring (register-resident; indices static via full unroll)
  float ring[PF];
  #pragma unroll
  for (int q = 0; q < PF; q++) ring[q] = cs[q * 64];
  // stage inbound boundary cols [0,64)
  if (s > 0) {
    while (__hip_atomic_load(&flags[s - 1], __ATOMIC_RELAXED, __HIP_MEMORY_SCOPE_AGENT) < 64) {}
    float bv = __hip_atomic_load(&bin[lane], __ATOMIC_RELAXED, __HIP_MEMORY_SCOPE_AGENT);
    bounce[(((lane - 9) & 127) << 6) + 63] = bv; // col c -> slot (c-9)&127
  }
  float Dcur = (s == 0 && lane == 0) ? 0.f : INFINITY; // Dcur doubles as D-left
  float Dul = INFINITY;
  float last4[4];
  float bval_pf = bounce[(((0 - 9) & 127) << 6) + rcol]; // boundary for t=0

  for (int W = 0; W < NW; W++) {
    const int t0 = W * 64;
    if (s > 0) { // stage inbound for the NEXT 64-step block
      int c0 = t0 + 64;
      if (c0 < IL) {
        int tgt = c0 + 64; if (tgt > IL) tgt = IL;
        while (__hip_atomic_load(&flags[s - 1], __ATOMIC_RELAXED, __HIP_MEMORY_SCOPE_AGENT) < tgt) {}
        float bv = __hip_atomic_load(&bin[c0 + lane], __ATOMIC_RELAXED, __HIP_MEMORY_SCOPE_AGENT);
        bounce[((((c0 + lane) - 9) & 127) << 6) + 63] = bv;
      }
    }
    if (W >= 2 && W < 128) {
      // main region: every lane active (t in [128, 8191] covers all skews)
      #pragma unroll
      for (int tt = 0; tt < 64; tt++) {
        const int t = t0 + tt;
        float cv = ring[tt & (PF - 1)];
        ring[tt & (PF - 1)] = cs[(t + PF) * 64];
        float bval = bval_pf;
        bval_pf = bounce[((((t + 1) - 9) & 127) << 6) + rcol];
        float Dup = f_dpp_shr1(bval, Dcur);
        float Dnew = cv + fminf(fminf(Dul, Dup), Dcur);
        Dul = Dup;
        Dcur = Dnew;
        bounce[(((t & 127) << 6) & wand) + wbase] = Dcur;
        last4[tt & 3] = Dcur;
        if ((tt & 3) == 2 && s < NS - 1) {
          if (lane == 63) {
            int j = t - 90;
            __hip_atomic_store(&bout[j + 0], last4[3], __ATOMIC_RELAXED, __HIP_MEMORY_SCOPE_AGENT);
            __hip_atomic_store(&bout[j + 1], last4[0], __ATOMIC_RELAXED, __HIP_MEMORY_SCOPE_AGENT);
            __hip_atomic_store(&bout[j + 2], last4[1], __ATOMIC_RELAXED, __HIP_MEMORY_SCOPE_AGENT);
            __hip_atomic_store(&bout[j + 3], last4[2], __ATOMIC_RELAXED, __HIP_MEMORY_SCOPE_AGENT);
          }
        }
      }
    } else {
      // masked prologue/epilogue
      #pragma unroll
      for (int tt = 0; tt < 64; tt++) {
        const int t = t0 + tt;
        float cv = ring[tt & (PF - 1)];
        int tl = t + PF; if (tl > TROWS - 1) tl = TROWS - 1;
        ring[tt & (PF - 1)] = cs[tl * 64];
        float bval = bval_pf;
        bval_pf = bounce[((((t + 1) - 9) & 127) << 6) + rcol];
        float Dup = f_dpp_shr1(bval, Dcur);
        float Dnew = cv + fminf(fminf(Dul, Dup), Dcur);
        bool a_lo = (t >= skew);
        bool a_hi = (t < IL + skew);
        Dul = a_lo ? Dup : Dul;
        Dcur = (a_lo && a_hi) ? Dnew : Dcur;
        bounce[(((t & 127) << 6) & wand) + wbase] = Dcur;
        last4[tt & 3] = Dcur;
        if ((tt & 3) == 2 && s < NS - 1 && t >= 90 && t <= 8278) {
          if (lane == 63) {
            int j = t - 90;
            __hip_atomic_store(&bout[j + 0], last4[3], __ATOMIC_RELAXED, __HIP_MEMORY_SCOPE_AGENT);
            __hip_atomic_store(&bout[j + 1], last4[0], __ATOMIC_RELAXED, __HIP_MEMORY_SCOPE_AGENT);
            __hip_atomic_store(&bout[j + 2], last4[1], __ATOMIC_RELAXED, __HIP_MEMORY_SCOPE_AGENT);
            __hip_atomic_store(&bout[j + 3], last4[2], __ATOMIC_RELAXED, __HIP_MEMORY_SCOPE_AGENT);
          }
        }
      }
    }
    // publish: only cols whose stores are >=64 VMEM-issues old (vmcnt<=63 => retired)
    if (s < NS - 1) {
      int cnt = (t0 - 90) & ~3;
      if (cnt > 0 && lane == 63)
        __hip_atomic_store(&flags[s], cnt, __ATOMIC_RELAXED, __HIP_MEMORY_SCOPE_AGENT);
    }
  }
  if (s < NS - 1) {
    __threadfence(); // drain everything once; then publish final count
    if (lane == 63)
      __hip_atomic_store(&flags[s], IL, __ATOMIC_RELAXED, __HIP_MEMORY_SCOPE_AGENT);
  }
  if (s == NS - 1 && lane == 63) out[0] = Dcur; // D[K-1][I-1] == path sum
}

extern "C" void kernel_launch(void* const* d_in, const int* in_sizes, int n_in,
                              void* d_out, int out_size, void* d_ws, size_t ws_size,
                              hipStream_t stream) {
  const float* kern = (const float*)d_in[0]; // (1024,128)
  const float* xx   = (const float*)d_in[1]; // (8192,128)
  char* ws = (char*)d_ws;
  const size_t OFF_X2 = (size_t)NS * SSTRIDE * 4;       // 33,914,880
  const size_t OFF_K2 = OFF_X2 + (size_t)IL * 4;
  const size_t OFF_BD = OFF_K2 + (size_t)KL * 4;
  const size_t OFF_FL = OFF_BD + (size_t)NS * IL * 4;   // total ~32.9 MiB
  float* c_sk  = (float*)ws;
  float* x2    = (float*)(ws + OFF_X2);
  float* k2    = (float*)(ws + OFF_K2);
  float* bnd   = (float*)(ws + OFF_BD);
  int*   flags = (int*)(ws + OFF_FL);

  knorms<<<(IL + KL) / 4, 256, 0, stream>>>(kern, xx, x2, k2, flags);
  kgemm<<<dim3(IL / 64, KL / 64), 256, 0, stream>>>(kern, xx, x2, k2, c_sk);
  kdp<<<NS, 64, 0, stream>>>(c_sk, bnd, flags, (float*)d_out);
}

// Round 2
// 534.154 us; speedup vs baseline: 1.9003x; 1.9003x over previous
//
#include <hip/hip_runtime.h>

#define KL 1024
#define IL 8192
#define DIMV 128
#define NS 16               // row strips of 64
#define TROWS 8320          // 8256 skewed rows used (max t=8254) + 64 pad for ring overrun
#define SSTRIDE (TROWS*64)  // floats per strip in c_sk
#define NW 129              // 129*64 = 8256 DP steps
#define PF 64               // c prefetch distance == block size
#define INF __builtin_inff()

// ---------------- kernel 1: squared row norms + zero flags ----------------
__global__ __launch_bounds__(256) void knorms(
    const float* __restrict__ kern, const float* __restrict__ xx,
    float* __restrict__ x2, float* __restrict__ k2, int* __restrict__ flags) {
  if (blockIdx.x == 0 && threadIdx.x < NS) flags[threadIdx.x] = 0;
  const int lane = threadIdx.x & 63;
  const int row = blockIdx.x * 4 + (threadIdx.x >> 6);
  const float* src;
  float* dst;
  if (row < IL) { src = xx + (size_t)row * DIMV; dst = x2 + row; }
  else          { src = kern + (size_t)(row - IL) * DIMV; dst = k2 + (row - IL); }
  float2 v = *(const float2*)(src + lane * 2);
  float ss = v.x * v.x + v.y * v.y;
  #pragma unroll
  for (int off = 32; off > 0; off >>= 1) ss += __shfl_down(ss, off, 64);
  if (lane == 0) *dst = ss;
}

// ---------------- kernel 2: c = max(x2 + k2 - 2*x·k, 0), diagonal-skew-stored ----------------
// c_sk[s][t][l] = c(row 64s+l, col j) with t = j + l  (pure diagonal skew)
__global__ __launch_bounds__(256) void kgemm(
    const float* __restrict__ kern, const float* __restrict__ xx,
    const float* __restrict__ x2, const float* __restrict__ k2,
    float* __restrict__ c_sk) {
  __shared__ float xs[128 * 68];
  __shared__ float ks[128 * 68];
  const int T = threadIdx.x;
  const int i0 = blockIdx.x * 64;  // x-row tile (DTW columns)
  const int k0 = blockIdx.y * 64;  // kernel-row tile (DTW rows)
  {
    const int rr = T >> 2;
    const int d0 = (T & 3) * 32;
    const float* xp = xx + (size_t)(i0 + rr) * DIMV + d0;
    const float* kp = kern + (size_t)(k0 + rr) * DIMV + d0;
    #pragma unroll
    for (int q = 0; q < 8; q++) {
      float4 a = *(const float4*)(xp + q * 4);
      float4 b = *(const float4*)(kp + q * 4);
      int d = d0 + q * 4;
      xs[(d+0)*68+rr] = a.x; xs[(d+1)*68+rr] = a.y; xs[(d+2)*68+rr] = a.z; xs[(d+3)*68+rr] = a.w;
      ks[(d+0)*68+rr] = b.x; ks[(d+1)*68+rr] = b.y; ks[(d+2)*68+rr] = b.z; ks[(d+3)*68+rr] = b.w;
    }
  }
  __syncthreads();
  const int ti = T & 15;
  const int tk = T >> 4;
  float acc[4][4] = {};
  #pragma unroll 4
  for (int d = 0; d < 128; d++) {
    float4 a = *(const float4*)&xs[d * 68 + ti * 4];
    float4 b = *(const float4*)&ks[d * 68 + tk * 4];
    acc[0][0] += a.x*b.x; acc[0][1] += a.x*b.y; acc[0][2] += a.x*b.z; acc[0][3] += a.x*b.w;
    acc[1][0] += a.y*b.x; acc[1][1] += a.y*b.y; acc[1][2] += a.y*b.z; acc[1][3] += a.y*b.w;
    acc[2][0] += a.z*b.x; acc[2][1] += a.z*b.y; acc[2][2] += a.z*b.z; acc[2][3] += a.z*b.w;
    acc[3][0] += a.w*b.x; acc[3][1] += a.w*b.y; acc[3][2] += a.w*b.z; acc[3][3] += a.w*b.w;
  }
  float xv[4], kv[4];
  #pragma unroll
  for (int a = 0; a < 4; a++) xv[a] = x2[i0 + ti * 4 + a];
  #pragma unroll
  for (int b = 0; b < 4; b++) kv[b] = k2[k0 + tk * 4 + b];
  __syncthreads();
  // tile[di][dk] = c(row k0+dk, col i0+di), reuse xs
  #pragma unroll
  for (int a = 0; a < 4; a++)
    #pragma unroll
    for (int b = 0; b < 4; b++)
      xs[(ti * 4 + a) * 64 + (tk * 4 + b)] = fmaxf(xv[a] + kv[b] - 2.f * acc[a][b], 0.f);
  __syncthreads();
  const int w = T >> 6;
  const int lane = T & 63;  // = dk (kernel-row within strip)
  float* ob = c_sk + (size_t)blockIdx.y * SSTRIDE + (size_t)i0 * 64 + lane;
  #pragma unroll
  for (int q = 0; q < 32; q++) {
    int tt = w + q * 4;           // skewed row within tile span [0,126]
    int di = tt - lane;
    if (tt <= 126 && di >= 0 && di < 64) ob[tt * 64] = xs[di * 64 + lane];
  }
}

// ---------------- kernel 3: wavefront DP, all-DPP (no LDS) ----------------
__device__ __forceinline__ float dpp_wave_shr1(float oldv, float src) {
  // lane i>0 reads lane i-1's src; lane 0 keeps oldv
  return __int_as_float(__builtin_amdgcn_update_dpp(
      __float_as_int(oldv), __float_as_int(src), 0x138, 0xF, 0xF, false));
}
__device__ __forceinline__ float dpp_wave_rol1(float src) {
  // lane i reads lane (i+1)&63 — data drifts toward lane 0
  return __int_as_float(__builtin_amdgcn_update_dpp(
      __float_as_int(src), __float_as_int(src), 0x134, 0xF, 0xF, false));
}
__device__ __forceinline__ float dpp_wave_shl1(float oldv, float src) {
  // lane i<63 reads lane i+1's src; lane 63 keeps oldv (injection point)
  return __int_as_float(__builtin_amdgcn_update_dpp(
      __float_as_int(oldv), __float_as_int(src), 0x130, 0xF, 0xF, false));
}

__global__ __launch_bounds__(64) void kdp(
    const float* __restrict__ c_sk, float* __restrict__ bound,
    int* __restrict__ flags, float* __restrict__ out) {
  const int s = blockIdx.x;
  const int lane = threadIdx.x;
  const float* cs = c_sk + (size_t)s * SSTRIDE + lane;
  float* bout = bound + (size_t)s * IL;
  const float* bin = bound + (size_t)(s - 1) * IL;

  // c prefetch ring: slot tt holds c for step (block_base + tt); fully unrolled -> registers
  float ring[PF];
  #pragma unroll
  for (int q = 0; q < PF; q++) ring[q] = cs[q * 64];

  // feed for block 0: lane l = D[64s-1][l] (strip above), INF border for strip 0
  float bb;
  if (s > 0) {
    while (__hip_atomic_load(&flags[s - 1], __ATOMIC_RELAXED, __HIP_MEMORY_SCOPE_AGENT) < 64) {}
    bb = __hip_atomic_load(&bin[lane], __ATOMIC_RELAXED, __HIP_MEMORY_SCOPE_AGENT);
  } else {
    bb = INF;
  }

  float Dcur = (s == 0 && lane == 0) ? 0.f : INF;  // doubles as D-left
  float Dul = INF;
  float Bv = bb;        // rotating feed: lane 0 holds b[t] at step t
  float Bout = INF;     // drifting collector: lane63 injects post-update Dcur
  float bb_next = INF;

  for (int W = 0; W < NW; W++) {
    const int t0 = W * 64;
    // prefetch feed for next block (lane0 inactive in block 128 -> skip W>=127)
    if (s > 0 && W < 127) {
      const int tgt = t0 + 128;
      while (__hip_atomic_load(&flags[s - 1], __ATOMIC_RELAXED, __HIP_MEMORY_SCOPE_AGENT) < tgt) {}
      bb_next = __hip_atomic_load(&bin[t0 + 64 + lane], __ATOMIC_RELAXED, __HIP_MEMORY_SCOPE_AGENT);
    }
    if (W >= 1 && W <= 127) {
      // main region: all 64 lanes active (t in [64,8191] => j=t-l in [0,8191] for all l)
      #pragma unroll
      for (int tt = 0; tt < 64; tt++) {
        const int t = t0 + tt;
        float cv = ring[tt];
        ring[tt] = cs[(size_t)(t + PF) * 64];
        float Dup = dpp_wave_shr1(Bv, Dcur);   // D[r-1][j] (lane0 from feed)
        Bv = dpp_wave_rol1(Bv);
        float Dnew = cv + fminf(fminf(Dul, Dup), Dcur);
        Dul = Dup;
        Dcur = Dnew;
        Bout = dpp_wave_shl1(Dcur, Bout);      // lane63 injects D[64s+63][t-63]
      }
    } else {
      // masked prologue (W=0) / epilogue (W=128)
      #pragma unroll
      for (int tt = 0; tt < 64; tt++) {
        const int t = t0 + tt;
        float cv = ring[tt];
        ring[tt] = cs[(size_t)(t + PF) * 64];
        float Dup = dpp_wave_shr1(Bv, Dcur);
        Bv = dpp_wave_rol1(Bv);
        float Dnew = cv + fminf(fminf(Dul, Dup), Dcur);
        const bool alo = (t >= lane);          // j >= 0
        const bool ahi = (t - lane < IL);      // j < IL
        if (alo) Dul = Dup;
        if (alo && ahi) Dcur = Dnew;
        Bout = dpp_wave_shl1(Dcur, Bout);
      }
    }
    if (s < NS - 1) {
      // Bout lane l = D[64s+63][t0 + l - 63]: one coalesced boundary store per block
      const int j = t0 + lane - 63;
      if (j >= 0 && j < IL)
        __hip_atomic_store(&bout[j], Bout, __ATOMIC_RELAXED, __HIP_MEMORY_SCOPE_AGENT);
      // publish coverage of block W-1 (its store is >=64 VMEM-issues old => retired in LLC)
      if (W >= 1 && lane == 0)
        __hip_atomic_store(&flags[s], 64 * (W - 1) + 1, __ATOMIC_RELAXED, __HIP_MEMORY_SCOPE_AGENT);
    }
    Bv = bb_next;
  }
  if (s < NS - 1) {
    __threadfence();  // drain all stores once, then publish full coverage
    if (lane == 0)
      __hip_atomic_store(&flags[s], IL, __ATOMIC_RELAXED, __HIP_MEMORY_SCOPE_AGENT);
  }
  if (s == NS - 1 && lane == 63) out[0] = Dcur;  // D[K-1][I-1] == optimal path sum
}

extern "C" void kernel_launch(void* const* d_in, const int* in_sizes, int n_in,
                              void* d_out, int out_size, void* d_ws, size_t ws_size,
                              hipStream_t stream) {
  const float* kern = (const float*)d_in[0]; // (1024,128)
  const float* xx   = (const float*)d_in[1]; // (8192,128)
  char* ws = (char*)d_ws;
  const size_t OFF_X2 = (size_t)NS * SSTRIDE * 4;       // c_sk: ~34.1 MB
  const size_t OFF_K2 = OFF_X2 + (size_t)IL * 4;
  const size_t OFF_BD = OFF_K2 + (size_t)KL * 4;
  const size_t OFF_FL = OFF_BD + (size_t)NS * IL * 4;
  float* c_sk  = (float*)ws;
  float* x2    = (float*)(ws + OFF_X2);
  float* k2    = (float*)(ws + OFF_K2);
  float* bnd   = (float*)(ws + OFF_BD);
  int*   flags = (int*)(ws + OFF_FL);

  knorms<<<(IL + KL) / 4, 256, 0, stream>>>(kern, xx, x2, k2, flags);
  kgemm<<<dim3(IL / 64, KL / 64), 256, 0, stream>>>(kern, xx, x2, k2, c_sk);
  kdp<<<NS, 64, 0, stream>>>(c_sk, bnd, flags, (float*)d_out);
}

// Round 3
// 509.431 us; speedup vs baseline: 1.9926x; 1.0485x over previous
//
#include <hip/hip_runtime.h>
#include <hip/hip_bf16.h>

#define KL 1024
#define IL 8192
#define DIMV 128
#define NS 16               // row strips of 64
#define TROWS 8320          // skewed rows per strip (max used t=8254) + pad for ring overrun
#define SSTRIDE (TROWS*64)  // floats per strip in c_sk
#define NW 129              // 129*64 = 8256 DP steps
#define PF 64               // c prefetch distance == block size
#define INF __builtin_inff()

typedef __attribute__((ext_vector_type(8))) short v8s;   // bf16x8 MFMA A/B frag
typedef __attribute__((ext_vector_type(4))) float v4f;   // MFMA C/D frag

// ---------------- kernel 1: squared row norms + zero flags ----------------
__global__ __launch_bounds__(256) void knorms(
    const float* __restrict__ kern, const float* __restrict__ xx,
    float* __restrict__ x2, float* __restrict__ k2, int* __restrict__ flags) {
  if (blockIdx.x == 0 && threadIdx.x < NS) flags[threadIdx.x] = 0;
  const int lane = threadIdx.x & 63;
  const int row = blockIdx.x * 4 + (threadIdx.x >> 6);
  const float* src;
  float* dst;
  if (row < IL) { src = xx + (size_t)row * DIMV; dst = x2 + row; }
  else          { src = kern + (size_t)(row - IL) * DIMV; dst = k2 + (row - IL); }
  float2 v = *(const float2*)(src + lane * 2);
  float ss = v.x * v.x + v.y * v.y;
  #pragma unroll
  for (int off = 32; off > 0; off >>= 1) ss += __shfl_down(ss, off, 64);
  if (lane == 0) *dst = ss;
}

// ---------------- kernel 2: MFMA bf16 GEMM -> c, diagonal-skew-stored ----------------
// c_sk[s][t][l] = c(row 64s+l, col j) with t = j + l
__device__ __forceinline__ v8s pack_bf16x8(float4 a, float4 b) {
  union { unsigned int u[4]; v8s v; } r;
  union { __hip_bfloat162 h; unsigned int u; } t;
  t.h = __float22bfloat162_rn(make_float2(a.x, a.y)); r.u[0] = t.u;
  t.h = __float22bfloat162_rn(make_float2(a.z, a.w)); r.u[1] = t.u;
  t.h = __float22bfloat162_rn(make_float2(b.x, b.y)); r.u[2] = t.u;
  t.h = __float22bfloat162_rn(make_float2(b.z, b.w)); r.u[3] = t.u;
  return r.v;
}

__global__ __launch_bounds__(256) void kgemm(
    const float* __restrict__ kern, const float* __restrict__ xx,
    const float* __restrict__ x2, const float* __restrict__ k2,
    float* __restrict__ c_sk) {
  __shared__ float ctile[64 * 64];
  const int T = threadIdx.x;
  const int w = T >> 6;            // wave: i-slice
  const int lane = T & 63;
  const int lo = lane & 15;
  const int hi = lane >> 4;
  const int i0 = blockIdx.x * 64;  // DTW columns (x rows)
  const int s  = blockIdx.y;       // strip
  const int kr0 = s * 64;          // DTW rows (kernel rows)

  v4f acc[4] = {};
  #pragma unroll
  for (int ks = 0; ks < 4; ks++) {
    const int k = ks * 32 + hi * 8;
    const float* bp = xx + (size_t)(i0 + w * 16 + lo) * DIMV + k;
    v8s bf = pack_bf16x8(*(const float4*)bp, *(const float4*)(bp + 4));
    #pragma unroll
    for (int rt = 0; rt < 4; rt++) {
      const float* ap = kern + (size_t)(kr0 + rt * 16 + lo) * DIMV + k;
      v8s af = pack_bf16x8(*(const float4*)ap, *(const float4*)(ap + 4));
      acc[rt] = __builtin_amdgcn_mfma_f32_16x16x32_bf16(af, bf, acc[rt], 0, 0, 0);
    }
  }
  // epilogue: c = max(k2 + x2 - 2*dot, 0) into swizzled LDS tile
  const float x2v = x2[i0 + w * 16 + lo];
  const int n_local = w * 16 + lo;
  #pragma unroll
  for (int rt = 0; rt < 4; rt++) {
    float4 k2f = *(const float4*)&k2[kr0 + rt * 16 + hi * 4];
    #pragma unroll
    for (int q = 0; q < 4; q++) {
      const int m_local = rt * 16 + hi * 4 + q;
      float cval = fmaxf((&k2f.x)[q] + x2v - 2.f * acc[rt][q], 0.f);
      ctile[n_local * 64 + ((m_local + 2 * n_local) & 63)] = cval;
    }
  }
  __syncthreads();
  // skew-scatter: global skewed row t = i0 + tt, lane l = kernel-row within strip
  float* ob = c_sk + (size_t)s * SSTRIDE + (size_t)i0 * 64 + lane;
  #pragma unroll
  for (int q = 0; q < 32; q++) {
    int tt = w + q * 4;            // local skewed row in [0,126]
    int di = tt - lane;            // i_local
    if (tt <= 126 && di >= 0 && di < 64)
      ob[tt * 64] = ctile[di * 64 + ((lane + 2 * di) & 63)];
  }
}

// ---------------- kernel 3: wavefront DP, all-DPP, non-draining polls ----------------
__device__ __forceinline__ float dpp_wave_shr1(float oldv, float src) {
  return __int_as_float(__builtin_amdgcn_update_dpp(
      __float_as_int(oldv), __float_as_int(src), 0x138, 0xF, 0xF, false));
}
__device__ __forceinline__ float dpp_wave_rol1(float src) {
  return __int_as_float(__builtin_amdgcn_update_dpp(
      __float_as_int(src), __float_as_int(src), 0x134, 0xF, 0xF, false));
}
__device__ __forceinline__ float dpp_wave_shl1(float oldv, float src) {
  return __int_as_float(__builtin_amdgcn_update_dpp(
      __float_as_int(oldv), __float_as_int(src), 0x130, 0xF, 0xF, false));
}

__global__ __launch_bounds__(64) void kdp(
    const float* __restrict__ c_sk, float* __restrict__ bound,
    int* __restrict__ flags, float* __restrict__ out) {
  const int s = blockIdx.x;
  const int lane = threadIdx.x;
  const float* cs = c_sk + (size_t)s * SSTRIDE + lane;
  float* bout = bound + (size_t)s * IL;
  const float* bin = bound + (size_t)(s - 1) * IL;

  // c prefetch ring (fully unrolled -> registers)
  float ring[PF];
  #pragma unroll
  for (int q = 0; q < PF; q++) ring[q] = cs[q * 64];

  float Bv, bb1;     // validated feed for current block; speculative feed for next
  int fchk = 0x7fffffff;
  if (s > 0) {
    int f;
    do { f = __hip_atomic_load(&flags[s - 1], __ATOMIC_RELAXED, __HIP_MEMORY_SCOPE_AGENT); } while (f < 128);
    Bv  = __hip_atomic_load(&bin[lane],      __ATOMIC_RELAXED, __HIP_MEMORY_SCOPE_AGENT);
    bb1 = __hip_atomic_load(&bin[64 + lane], __ATOMIC_RELAXED, __HIP_MEMORY_SCOPE_AGENT);
    fchk = f;
  } else {
    Bv = INF; bb1 = INF;
  }

  float Dcur = (s == 0 && lane == 0) ? 0.f : INF;  // doubles as D-left
  float Dul = INF;
  float Bout = INF;

  for (int W = 0; W < NW; W++) {
    const int t0 = W * 64;
    float bb2 = INF;
    int fnew = fchk;
    if (s > 0 && W < NW - 1) {
      // validate bb1 (feed for block W+1) using the flag snapshot from last block.
      // Common path: fchk already >= need -> no memory wait at all.
      int need = t0 + 128; if (need > IL) need = IL;
      if (fchk < need) {  // slow path (pipeline fill only)
        int f;
        do { f = __hip_atomic_load(&flags[s - 1], __ATOMIC_RELAXED, __HIP_MEMORY_SCOPE_AGENT); } while (f < need);
        int rb = t0 + 64; if (rb > IL - 64) rb = IL - 64;
        bb1 = __hip_atomic_load(&bin[rb + lane], __ATOMIC_RELAXED, __HIP_MEMORY_SCOPE_AGENT);
        fchk = f;
      }
      // speculative issue for block W+2 (validated next block; consumed block after)
      int nb = t0 + 128; if (nb > IL - 64) nb = IL - 64;
      bb2  = __hip_atomic_load(&bin[nb + lane], __ATOMIC_RELAXED, __HIP_MEMORY_SCOPE_AGENT);
      fnew = __hip_atomic_load(&flags[s - 1],   __ATOMIC_RELAXED, __HIP_MEMORY_SCOPE_AGENT);
    }
    if (W >= 1 && W <= 127) {
      // main region: all 64 lanes in range
      #pragma unroll
      for (int tt = 0; tt < 64; tt++) {
        const int t = t0 + tt;
        float cv = ring[tt];
        ring[tt] = cs[(size_t)(t + PF) * 64];
        float Dup = dpp_wave_shr1(Bv, Dcur);   // D[r-1][j]; lane0 from feed
        Bv = dpp_wave_rol1(Bv);
        float Dnew = cv + fminf(fminf(Dul, Dup), Dcur);
        Dul = Dup;
        Dcur = Dnew;
        Bout = dpp_wave_shl1(Dcur, Bout);      // lane63 injects bottom-row value
      }
    } else {
      // masked prologue (W=0) / epilogue (W=128)
      #pragma unroll
      for (int tt = 0; tt < 64; tt++) {
        const int t = t0 + tt;
        float cv = ring[tt];
        ring[tt] = cs[(size_t)(t + PF) * 64];
        float Dup = dpp_wave_shr1(Bv, Dcur);
        Bv = dpp_wave_rol1(Bv);
        float Dnew = cv + fminf(fminf(Dul, Dup), Dcur);
        const bool alo = (t >= lane);          // j >= 0
        const bool ahi = (t - lane < IL);      // j < IL
        if (alo) Dul = Dup;
        if (alo && ahi) Dcur = Dnew;
        Bout = dpp_wave_shl1(Dcur, Bout);
      }
    }
    if (s < NS - 1) {
      // coalesced boundary store for this block
      const int j = t0 + lane - 63;
      if (j >= 0 && j < IL)
        __hip_atomic_store(&bout[j], Bout, __ATOMIC_RELAXED, __HIP_MEMORY_SCOPE_AGENT);
      // publish coverage of block W-1 (its store is >=64 vmem ops old => retired)
      if (W >= 1 && lane == 0)
        __hip_atomic_store(&flags[s], 64 * (W - 1) + 1, __ATOMIC_RELAXED, __HIP_MEMORY_SCOPE_AGENT);
    }
    if (s > 0) { Bv = bb1; bb1 = bb2; fchk = fnew; }
  }
  if (s < NS - 1) {
    __threadfence();  // drain all stores once, then publish full coverage
    if (lane == 0)
      __hip_atomic_store(&flags[s], IL, __ATOMIC_RELAXED, __HIP_MEMORY_SCOPE_AGENT);
  }
  if (s == NS - 1 && lane == 63) out[0] = Dcur;  // D[K-1][I-1] == optimal path sum
}

extern "C" void kernel_launch(void* const* d_in, const int* in_sizes, int n_in,
                              void* d_out, int out_size, void* d_ws, size_t ws_size,
                              hipStream_t stream) {
  const float* kern = (const float*)d_in[0]; // (1024,128)
  const float* xx   = (const float*)d_in[1]; // (8192,128)
  char* ws = (char*)d_ws;
  const size_t OFF_X2 = (size_t)NS * SSTRIDE * 4;       // c_sk: ~34.1 MB
  const size_t OFF_K2 = OFF_X2 + (size_t)IL * 4;
  const size_t OFF_BD = OFF_K2 + (size_t)KL * 4;
  const size_t OFF_FL = OFF_BD + (size_t)NS * IL * 4;
  float* c_sk  = (float*)ws;
  float* x2    = (float*)(ws + OFF_X2);
  float* k2    = (float*)(ws + OFF_K2);
  float* bnd   = (float*)(ws + OFF_BD);
  int*   flags = (int*)(ws + OFF_FL);

  knorms<<<(IL + KL) / 4, 256, 0, stream>>>(kern, xx, x2, k2, flags);
  kgemm<<<dim3(IL / 64, NS), 256, 0, stream>>>(kern, xx, x2, k2, c_sk);
  kdp<<<NS, 64, 0, stream>>>(c_sk, bnd, flags, (float*)d_out);
}